// Round 2
// 542.383 us; speedup vs baseline: 1.0348x; 1.0348x over previous
//
#include <hip/hip_runtime.h>

static constexpr int T_STEPS = 512;
static constexpr int NBATCH  = 256;
static constexpr int DD      = 128;                         // C = D = K = 128
static constexpr long TND    = (long)T_STEPS * NBATCH * DD; // elems per output tensor

typedef short bf16x8 __attribute__((ext_vector_type(8)));   // 8 bf16 in 4 VGPRs
typedef float f32x4  __attribute__((ext_vector_type(4)));
typedef unsigned u32x4 __attribute__((ext_vector_type(4)));

__device__ inline unsigned short f2bf(float f) {            // RNE fp32 -> bf16
  unsigned u = __builtin_bit_cast(unsigned, f);
  unsigned r = u + 0x7FFFu + ((u >> 16) & 1u);
  return (unsigned short)(r >> 16);
}

__device__ inline bf16x8 pack8(const float* s) {
  bf16x8 v;
#pragma unroll
  for (int i = 0; i < 8; ++i) v[i] = (short)f2bf(s[i]);
  return v;
}

// v_cvt_pk_bf16_f32: D.lo = bf16(lo), D.hi = bf16(hi), RNE (gfx950).
__device__ __forceinline__ unsigned cvtpk_bf16(float lo, float hi) {
  unsigned r;
  asm("v_cvt_pk_bf16_f32 %0, %1, %2" : "=v"(r) : "v"(lo), "v"(hi));
  return r;
}

// ---------------------------------------------------------------------------
// Phase 1 / 3: O[M x 128] = A[M x 128] @ W^T + bias via bf16 MFMA, fp32 accum.
// One wave owns all of W as 32 register-resident B-fragments (128 VGPRs),
// then grid-strides over 16-row tiles: 8 A-loads + 32 MFMA + 32 stores/tile.
// Layouts (m89/m120-verified): A/B frag [lane&15][quad*8+j]; D col=lane&15,
// row=quad*4+reg.
// ---------------------------------------------------------------------------
__global__ __launch_bounds__(256) void gemm128_mfma(
    const float* __restrict__ A, const float* __restrict__ W,
    const float* __restrict__ bias, float* __restrict__ O, int ntiles) {
  const int lane = threadIdx.x & 63;
  const int wib  = threadIdx.x >> 6;     // wave in block (0..3)
  const int m    = lane & 15;            // row-in-tile / W-row-in-dtile
  const int q    = lane >> 4;            // quad: k-octet selector, C row group

  // B-frags: Wf[j][kq] = W[j*16+m][kq*32 + q*8 .. +7]  (all of W, bf16)
  bf16x8 Wf[8][4];
#pragma unroll
  for (int j = 0; j < 8; ++j)
#pragma unroll
    for (int kq = 0; kq < 4; ++kq) {
      const float* p = W + (j * 16 + m) * DD + kq * 32 + q * 8;
      float t[8];
      *(float4*)&t[0] = *(const float4*)p;
      *(float4*)&t[4] = *(const float4*)(p + 4);
      Wf[j][kq] = pack8(t);
    }
  float bv[8];
#pragma unroll
  for (int j = 0; j < 8; ++j) bv[j] = bias[j * 16 + m];

  const int wglobal = blockIdx.x * 4 + wib;
  const int nwaves  = gridDim.x * 4;
  for (int tile = wglobal; tile < ntiles; tile += nwaves) {
    const long r0 = (long)tile * 16;
    f32x4 acc[8];
#pragma unroll
    for (int j = 0; j < 8; ++j) acc[j] = (f32x4){0.f, 0.f, 0.f, 0.f};

#pragma unroll
    for (int kq = 0; kq < 4; ++kq) {
      const float* p = A + (r0 + m) * DD + kq * 32 + q * 8;
      float t[8];
      *(float4*)&t[0] = *(const float4*)p;
      *(float4*)&t[4] = *(const float4*)(p + 4);
      bf16x8 af = pack8(t);
#pragma unroll
      for (int j = 0; j < 8; ++j)
        acc[j] = __builtin_amdgcn_mfma_f32_16x16x32_bf16(af, Wf[j][kq], acc[j], 0, 0, 0);
    }
    // D[row=q*4+r][col=j*16+m] -> O, + bias
#pragma unroll
    for (int j = 0; j < 8; ++j)
#pragma unroll
      for (int r = 0; r < 4; ++r)
        O[(r0 + q * 4 + r) * DD + j * 16 + m] = acc[j][r] + bv[j];
  }
}

// ---------------------------------------------------------------------------
// Phase 2: sequential scan on the MATRIX pipe, one wave per 16 batch rows.
// Orientation: D[d][n] = sum_k Wh[d][k] * h[n][k]  (Wh = A/M-side, h^T = B).
// D layout keeps each lane's batch row n = lane&15 fixed across steps, so the
// only step-to-step data movement is a k-repack within the lane. MFMA pairs
// A and B strictly by (q,position) slot, so we apply the SAME per-q
// k-permutation kappa(q,jj) = 32kq + 16*(jj>>2) + 4q + (jj&3) to both sides:
//   - Wh A-frags are gathered once with that layout (register-resident);
//   - the step's D quads, packed pairwise to bf16, ARE the next step's
//     B-frags directly. No shuffle, no LDS, no barrier in the whole scan.
// xp is folded in as the accumulator init (prefetched 4 steps ahead through
// a named ring -> covers HBM-miss latency; no runtime-indexed reg arrays).
// h is stored fp32 in place (same addresses as the xp loads).
// ---------------------------------------------------------------------------
__global__ __launch_bounds__(64, 1) void rnn_scan_mfma(
    const float* __restrict__ Wh, float* __restrict__ H /* [T][N][128] xp->h */) {
  const int lane = threadIdx.x & 63;
  const int m = lane & 15;   // batch row within the wave's 16-row group
  const int q = lane >> 4;   // quad

  // A-frags with the q-dependent kappa gather:
  // short s<4  -> Wh[16j+m][32kq + 4q + s]
  // short s>=4 -> Wh[16j+m][32kq + 16 + 4q + (s-4)]
  bf16x8 Whf[8][4];
#pragma unroll
  for (int j = 0; j < 8; ++j)
#pragma unroll
    for (int kq = 0; kq < 4; ++kq) {
      const float* p = Wh + (j * 16 + m) * DD + kq * 32 + 4 * q;
      float t[8];
      *(float4*)&t[0] = *(const float4*)p;
      *(float4*)&t[4] = *(const float4*)(p + 16);
      Whf[j][kq] = pack8(t);
    }

  const long stepN = (long)NBATCH * DD;
  float* base = H + (long)(blockIdx.x * 16 + m) * DD + 4 * q;

  // w[j][h] = bf16x2 of (h[m][16j+4q+2h], h[m][16j+4q+2h+1]); h_{-1} = 0.
  unsigned w[8][2];
#pragma unroll
  for (int j = 0; j < 8; ++j) { w[j][0] = 0u; w[j][1] = 0u; }

  auto pref = [&](f32x4 (&xp)[8], int t) {
    const float* pp = base + (long)t * stepN;
#pragma unroll
    for (int j = 0; j < 8; ++j) xp[j] = *(const f32x4*)(pp + j * 16);
  };

  auto step = [&](const f32x4 (&xp)[8], int t) {
    f32x4 acc[8];
#pragma unroll
    for (int j = 0; j < 8; ++j) acc[j] = xp[j];   // fold +xp into C-init
#pragma unroll
    for (int kq = 0; kq < 4; ++kq) {
      u32x4 bw;
      bw[0] = w[2 * kq][0];     bw[1] = w[2 * kq][1];
      bw[2] = w[2 * kq + 1][0]; bw[3] = w[2 * kq + 1][1];
      bf16x8 bf = __builtin_bit_cast(bf16x8, bw);
#pragma unroll
      for (int j = 0; j < 8; ++j)
        acc[j] = __builtin_amdgcn_mfma_f32_16x16x32_bf16(Whf[j][kq], bf, acc[j], 0, 0, 0);
    }
    float* hp = base + (long)t * stepN;
#pragma unroll
    for (int j = 0; j < 8; ++j) {   // relu, repack for next step, store fp32
      f32x4 hv;
#pragma unroll
      for (int r = 0; r < 4; ++r) hv[r] = fmaxf(acc[j][r], 0.f);
      w[j][0] = cvtpk_bf16(hv[0], hv[1]);
      w[j][1] = cvtpk_bf16(hv[2], hv[3]);
      *(f32x4*)(hp + j * 16) = hv;
    }
  };

  f32x4 xA[8], xB[8], xC[8], xD[8];   // 4-deep named prefetch ring
  pref(xA, 0); pref(xB, 1); pref(xC, 2); pref(xD, 3);

#pragma unroll 1
  for (int t = 0; t < T_STEPS; t += 4) {
    step(xA, t);     pref(xA, t + 4 < T_STEPS ? t + 4 : T_STEPS - 1);
    step(xB, t + 1); pref(xB, t + 5 < T_STEPS ? t + 5 : T_STEPS - 1);
    step(xC, t + 2); pref(xC, t + 6 < T_STEPS ? t + 6 : T_STEPS - 1);
    step(xD, t + 3); pref(xD, t + 7 < T_STEPS ? t + 7 : T_STEPS - 1);
  }
}

// ---------------------------------------------------------------------------
extern "C" void kernel_launch(void* const* d_in, const int* in_sizes, int n_in,
                              void* d_out, int out_size, void* d_ws, size_t ws_size,
                              hipStream_t stream) {
  const float* x  = (const float*)d_in[0];   // (T,N,C)
  const float* Wx = (const float*)d_in[1];   // (D,C)
  const float* bx = (const float*)d_in[2];   // (D)
  const float* Wh = (const float*)d_in[3];   // (D,D)
  const float* Wy = (const float*)d_in[4];   // (K,D)
  const float* by = (const float*)d_in[5];   // (K)

  float* Y = (float*)d_out;        // all_y: [T][N][K]
  float* H = (float*)d_out + TND;  // all_h: [T][N][D]

  const int ntiles = T_STEPS * NBATCH / 16;  // 8192 row-tiles

  gemm128_mfma<<<512, 256, 0, stream>>>(x, Wx, bx, H, ntiles);   // xproj -> H
  rnn_scan_mfma<<<NBATCH / 16, 64, 0, stream>>>(Wh, H);          // in-place xp -> h
  gemm128_mfma<<<512, 256, 0, stream>>>(H, Wy, by, Y, ntiles);   // all_y
}